// Round 9
// baseline (46.570 us; speedup 1.0000x reference)
//
#include <hip/hip_runtime.h>

// HungarianMatcher cost matrix: C[n,m] = 5*L1(boxes) + 2*focal_class - 2*GIoU
// logits [N=16000, NC=256] f32, pred_boxes [N,4] cxcywh f32,
// tgt_labels [M=1600] i32, tgt_boxes [M,4] cxcywh f32, out [N,M] f32.

constexpr float ALPHAc = 0.25f;
constexpr float EPSc   = 1e-8f;

constexpr int NC  = 256;  // classes (== blockDim.x)
constexpr int NT  = 256;  // threads per block
constexpr int RPB = 4;    // rows per block (16000 % 4 == 0 -> 4000 full blocks)

typedef float f32x4 __attribute__((ext_vector_type(4)));
typedef float f32x2 __attribute__((ext_vector_type(2)));

struct TBox { float x0, y0, x1, y1, area; };

__device__ __forceinline__ TBox make_box(float4 b) {
    TBox r;
    r.x0 = fmaf(-0.5f, b.z, b.x);
    r.y0 = fmaf(-0.5f, b.w, b.y);
    r.x1 = fmaf( 0.5f, b.z, b.x);
    r.y1 = fmaf( 0.5f, b.w, b.y);
    r.area = b.z * b.w;
    return r;
}

struct RowP { float px0, py0, px1, py1, parea, pw2, ph2; };

__device__ __forceinline__ RowP make_row(float4 pb) {
    RowP r;
    r.px0 = fmaf(-0.5f, pb.z, pb.x);
    r.py0 = fmaf(-0.5f, pb.w, pb.y);
    r.px1 = fmaf( 0.5f, pb.z, pb.x);
    r.py1 = fmaf( 0.5f, pb.w, pb.y);
    r.parea = pb.z * pb.w;
    r.pw2 = pb.z + pb.z;
    r.ph2 = pb.w + pb.w;
    return r;
}

__device__ __forceinline__ const float* fc_base(const float* fc0, int c) {
    c = c < 0 ? 0 : (c > NC - 1 ? NC - 1 : c);
    return fc0 + c;
}

// res = 5*L1 + (2*fc+2) - 2*(inter/uni + uni/carea)
__device__ __forceinline__ float cost_elem(const RowP& p, const TBox& b, float fcp) {
    const float u0 = b.x0 - p.px0, u1 = b.x1 - p.px1;
    const float v0 = b.y0 - p.py0, v1 = b.y1 - p.py1;
    const float du = u1 - u0,      dv = v1 - v0;
    const float l1 = fmaf(0.5f, fabsf(u0 + u1), fabsf(du))
                   + fmaf(0.5f, fabsf(v0 + v1), fabsf(dv));
    const float ix0 = fmaxf(p.px0, b.x0), ix1 = fminf(p.px1, b.x1);
    const float iy0 = fmaxf(p.py0, b.y0), iy1 = fminf(p.py1, b.y1);
    const float iwr = ix1 - ix0, ihr = iy1 - iy0;
    const float inter = fmaxf(iwr, 0.0f) * fmaxf(ihr, 0.0f);
    const float uni   = (p.parea + b.area) - inter;
    const float cw = (p.pw2 + du) - iwr;
    const float ch = (p.ph2 + dv) - ihr;
    const float carea = cw * ch;
    const float num = fmaf(uni, uni, inter * carea);
    const float mm  = num * __builtin_amdgcn_rcpf(uni * carea);
    return fmaf(-2.0f, mm, fmaf(5.0f, l1, fcp));
}

__global__ __launch_bounds__(NT)
void hungarian_cost_kernel(const float* __restrict__ logits,
                           const float* __restrict__ pboxes,
                           const int*   __restrict__ tlabels,
                           const float* __restrict__ tboxes,
                           float*       __restrict__ out,
                           int N, int M)
{
    const int t  = threadIdx.x;
    const int n0 = blockIdx.x * RPB;
    if (n0 >= N) return;
    const int rows = (N - n0 < RPB) ? (N - n0) : RPB;

    __shared__ float fc[RPB][NC];   // 2*focal+2, per row per class (4 KB)

    const float4* tb4 = reinterpret_cast<const float4*>(tboxes);
    const float*  fc0 = &fc[0][0];

    // m-layout: nA float4 groups, nB float2 groups, scalar tail.
    // M=1600: 256*4 + 256*2 + 64*1.
    const int nA    = (M >> 2) < NT ? (M >> 2) : NT;
    const int baseB = 4 * nA;
    const int nB    = ((M - baseB) >> 1) < NT ? ((M - baseB) >> 1) : NT;
    const int baseC = baseB + 2 * nB;
    const bool aV = t < nA;
    const bool bV = t < nB;
    const bool cV = (baseC + t) < M;

    // ---- Issue ALL VMEM loads before any store (loads/stores share vmcnt
    //      in order; a load issued after stores forces a store drain). ----
    float4 rawA[4]; int4 cA = {0, 0, 0, 0};
    if (aV) {
        cA = reinterpret_cast<const int4*>(tlabels)[t];
        rawA[0] = tb4[4 * t + 0];
        rawA[1] = tb4[4 * t + 1];
        rawA[2] = tb4[4 * t + 2];
        rawA[3] = tb4[4 * t + 3];
    }
    float4 rawB[2]; int2 cB = {0, 0};
    if (bV) {
        cB = reinterpret_cast<const int2*>(tlabels + baseB)[t];
        rawB[0] = tb4[baseB + 2 * t + 0];
        rawB[1] = tb4[baseB + 2 * t + 1];
    }
    float4 rawC = {0, 0, 0, 0}; int cC = 0;
    if (cV) {
        cC = tlabels[baseC + t];
        rawC = tb4[baseC + t];
    }
    float4 pbr[RPB];   // uniform-indexed -> scalar loads
#pragma unroll
    for (int r = 0; r < RPB; ++r)
        pbr[r] = reinterpret_cast<const float4*>(pboxes)[n0 + (r < rows ? r : 0)];

    // ---- Focal costs for all rows. ONE barrier. ----
#pragma unroll
    for (int r = 0; r < RPB; ++r) {
        if (r < rows) {
            const float x = logits[(size_t)(n0 + r) * NC + t];
            const float p = __builtin_amdgcn_rcpf(1.0f + __expf(-x));
            const float q = 1.0f - p;
            const float pos = ALPHAc * q * q * (-__logf(p + EPSc));
            const float neg = (1.0f - ALPHAc) * p * p * (-__logf(q + EPSc));
            fc[r][t] = fmaf(2.0f, pos - neg, 2.0f);
        }
    }
    __syncthreads();

    if (rows == RPB) {
        // ===================== straight-line fast path =====================
        // Post-barrier: only VALU + ds_read + nt-stores. No VMEM loads.

        // ---- Phase A: 4 targets/thread, float4 stores. ----
        if (aV) {
            const TBox b0 = make_box(rawA[0]);
            const TBox b1 = make_box(rawA[1]);
            const TBox b2 = make_box(rawA[2]);
            const TBox b3 = make_box(rawA[3]);
            const float* g0 = fc_base(fc0, cA.x);
            const float* g1 = fc_base(fc0, cA.y);
            const float* g2 = fc_base(fc0, cA.z);
            const float* g3 = fc_base(fc0, cA.w);
            float fA[RPB][4];               // statically indexed -> registers
#pragma unroll
            for (int r = 0; r < RPB; ++r) { // 16 ds_read_b32 issued up-front
                fA[r][0] = g0[r * NC];
                fA[r][1] = g1[r * NC];
                fA[r][2] = g2[r * NC];
                fA[r][3] = g3[r * NC];
            }
#pragma unroll
            for (int r = 0; r < RPB; ++r) {
                const RowP p = make_row(pbr[r]);
                f32x4 res;
                res.x = cost_elem(p, b0, fA[r][0]);
                res.y = cost_elem(p, b1, fA[r][1]);
                res.z = cost_elem(p, b2, fA[r][2]);
                res.w = cost_elem(p, b3, fA[r][3]);
                float* orow = out + (size_t)(n0 + r) * M;
                __builtin_nontemporal_store(res, reinterpret_cast<f32x4*>(orow) + t);
            }
        }

        // ---- Phase B: 2 targets/thread, float2 stores. ----
        if (bV) {
            const TBox b0 = make_box(rawB[0]);
            const TBox b1 = make_box(rawB[1]);
            const float* g0 = fc_base(fc0, cB.x);
            const float* g1 = fc_base(fc0, cB.y);
            float fB[RPB][2];
#pragma unroll
            for (int r = 0; r < RPB; ++r) {
                fB[r][0] = g0[r * NC];
                fB[r][1] = g1[r * NC];
            }
#pragma unroll
            for (int r = 0; r < RPB; ++r) {
                const RowP p = make_row(pbr[r]);
                f32x2 res;
                res.x = cost_elem(p, b0, fB[r][0]);
                res.y = cost_elem(p, b1, fB[r][1]);
                float* orow = out + (size_t)(n0 + r) * M + baseB;
                __builtin_nontemporal_store(res, reinterpret_cast<f32x2*>(orow) + t);
            }
        }

        // ---- Phase C: scalar tail (64 lanes for M=1600). ----
        if (cV) {
            const int e = baseC + t;
            const TBox b = make_box(rawC);
            const float* g = fc_base(fc0, cC);
            float fC[RPB];
#pragma unroll
            for (int r = 0; r < RPB; ++r) fC[r] = g[r * NC];
#pragma unroll
            for (int r = 0; r < RPB; ++r) {
                const RowP p = make_row(pbr[r]);
                const float v = cost_elem(p, b, fC[r]);
                __builtin_nontemporal_store(v, out + (size_t)(n0 + r) * M + e);
            }
        }
        // Extra tail beyond one stride (not hit for M=1600).
        for (int e = baseC + NT + t; e < M; e += NT) {
            const TBox b = make_box(tb4[e]);
            const float* g = fc_base(fc0, tlabels[e]);
#pragma unroll
            for (int r = 0; r < RPB; ++r) {
                const RowP p = make_row(pbr[r]);
                const float v = cost_elem(p, b, g[r * NC]);
                __builtin_nontemporal_store(v, out + (size_t)(n0 + r) * M + e);
            }
        }
    } else {
        // ===================== generic fallback (never hit for N=16000) =====
        for (int r = 0; r < rows; ++r) {
            const RowP p = make_row(pbr[r]);
            for (int e = t; e < M; e += NT) {
                const TBox b = make_box(tb4[e]);
                const float f = *fc_base(fc0 + r * NC, tlabels[e]);
                out[(size_t)(n0 + r) * M + e] = cost_elem(p, b, f);
            }
        }
    }
}

extern "C" void kernel_launch(void* const* d_in, const int* in_sizes, int n_in,
                              void* d_out, int out_size, void* d_ws, size_t ws_size,
                              hipStream_t stream) {
    const float* logits  = (const float*)d_in[0];   // [16,1000,256] f32
    const float* pboxes  = (const float*)d_in[1];   // [16,1000,4]  f32
    const int*   tlabels = (const int*)d_in[2];     // [1600] i32
    const float* tboxes  = (const float*)d_in[3];   // [1600,4] f32

    float* out = (float*)d_out;

    const int N = in_sizes[1] / 4;   // 16000 pred rows
    const int M = in_sizes[2];       // 1600 targets

    const int nblocks = (N + RPB - 1) / RPB;   // 4000
    hipLaunchKernelGGL(hungarian_cost_kernel, dim3(nblocks), dim3(NT), 0, stream,
                       logits, pboxes, tlabels, tboxes, out, N, M);
}

// Round 10
// 42.950 us; speedup vs baseline: 1.0843x; 1.0843x over previous
//
#include <hip/hip_runtime.h>

// HungarianMatcher cost matrix: C[n,m] = 5*L1(boxes) + 2*focal_class - 2*GIoU
// logits [N=16000, NC=256] f32, pred_boxes [N,4] cxcywh f32,
// tgt_labels [M=1600] i32, tgt_boxes [M,4] cxcywh f32, out [N,M] f32.
//
// Persistent-wg version: 500 wgs x 4 tiles (RPB=8 rows each). Targets cached
// in registers once per wg; next tile's logits/pbox prefetched before the
// current tile's stores so the prologue HBM latency hides under phase compute.

constexpr float ALPHAc = 0.25f;
constexpr float EPSc   = 1e-8f;

constexpr int NC    = 256;  // classes (== blockDim.x)
constexpr int NT    = 256;  // threads per block
constexpr int RPB   = 8;    // rows per tile
constexpr int MAXWG = 500;  // persistent workgroups

typedef float f32x4 __attribute__((ext_vector_type(4)));
typedef float f32x2 __attribute__((ext_vector_type(2)));

struct TBox { float x0, y0, x1, y1, area; };

__device__ __forceinline__ TBox make_box(float4 b) {
    TBox r;
    r.x0 = fmaf(-0.5f, b.z, b.x);
    r.y0 = fmaf(-0.5f, b.w, b.y);
    r.x1 = fmaf( 0.5f, b.z, b.x);
    r.y1 = fmaf( 0.5f, b.w, b.y);
    r.area = b.z * b.w;
    return r;
}

__device__ __forceinline__ int clamp_cls(int c) {
    return c < 0 ? 0 : (c > NC - 1 ? NC - 1 : c);
}

// res = 5*L1 + (2*fc+2) - 2*(inter/uni + uni/carea)
//  L1 on cxcywh from xyxy: 0.5|u0+u1| + |u1-u0| per axis.
//  Enclosing width identity: cw = 2pw + (u1-u0) - iwr.
//  Single reciprocal: inter/uni + uni/carea = (uni^2 + inter*carea)/(uni*carea).
__device__ __forceinline__ float cost_elem(float px0, float py0, float px1, float py1,
                                           float parea, float pw2, float ph2,
                                           const TBox& b, float fcp) {
    const float u0 = b.x0 - px0, u1 = b.x1 - px1;
    const float v0 = b.y0 - py0, v1 = b.y1 - py1;
    const float du = u1 - u0,    dv = v1 - v0;
    const float l1 = fmaf(0.5f, fabsf(u0 + u1), fabsf(du))
                   + fmaf(0.5f, fabsf(v0 + v1), fabsf(dv));
    const float ix0 = fmaxf(px0, b.x0), ix1 = fminf(px1, b.x1);
    const float iy0 = fmaxf(py0, b.y0), iy1 = fminf(py1, b.y1);
    const float iwr = ix1 - ix0, ihr = iy1 - iy0;
    const float inter = fmaxf(iwr, 0.0f) * fmaxf(ihr, 0.0f);
    const float uni   = (parea + b.area) - inter;
    const float cw = (pw2 + du) - iwr;
    const float ch = (ph2 + dv) - ihr;
    const float carea = cw * ch;
    const float num = fmaf(uni, uni, inter * carea);
    const float mm  = num * __builtin_amdgcn_rcpf(uni * carea);
    return fmaf(-2.0f, mm, fmaf(5.0f, l1, fcp));
}

__global__ __launch_bounds__(NT)
void hungarian_cost_kernel(const float* __restrict__ logits,
                           const float* __restrict__ pboxes,
                           const int*   __restrict__ tlabels,
                           const float* __restrict__ tboxes,
                           float*       __restrict__ out,
                           int N, int M)
{
    const int t        = threadIdx.x;
    const int nwg      = gridDim.x;
    const int numTiles = (N + RPB - 1) / RPB;

    __shared__ float fc[2][RPB][NC];  // 2*focal+2 (double-buffered)
    __shared__ float pp[2][RPB][8];   // px0,py0,px1,py1,parea,pw2,ph2,pad

    const float4* tb4 = reinterpret_cast<const float4*>(tboxes);
    const float4* pb4 = reinterpret_cast<const float4*>(pboxes);

    // m-layout: nA float4 groups, nB float2 groups, scalar tail.
    // M=1600: 256*4 + 256*2 + 64*1.
    const int nA    = (M >> 2) < NT ? (M >> 2) : NT;
    const int baseB = 4 * nA;
    const int nB    = ((M - baseB) >> 1) < NT ? ((M - baseB) >> 1) : NT;
    const int baseC = baseB + 2 * nB;
    const bool aV = t < nA;
    const bool bV = t < nB;
    const bool cV = (baseC + t) < M;

    // ---- Per-wg target cache: loaded + converted ONCE, reused for all tiles.
    TBox bA0 = {}, bA1 = {}, bA2 = {}, bA3 = {}, bB0 = {}, bB1 = {}, bC = {};
    int cA0 = 0, cA1 = 0, cA2 = 0, cA3 = 0, cB0 = 0, cB1 = 0, cC = 0;
    if (aV) {
        const int4 c4 = reinterpret_cast<const int4*>(tlabels)[t];
        bA0 = make_box(tb4[4 * t + 0]);
        bA1 = make_box(tb4[4 * t + 1]);
        bA2 = make_box(tb4[4 * t + 2]);
        bA3 = make_box(tb4[4 * t + 3]);
        cA0 = clamp_cls(c4.x); cA1 = clamp_cls(c4.y);
        cA2 = clamp_cls(c4.z); cA3 = clamp_cls(c4.w);
    }
    if (bV) {
        const int2 c2 = reinterpret_cast<const int2*>(tlabels + baseB)[t];
        bB0 = make_box(tb4[baseB + 2 * t + 0]);
        bB1 = make_box(tb4[baseB + 2 * t + 1]);
        cB0 = clamp_cls(c2.x); cB1 = clamp_cls(c2.y);
    }
    if (cV) {
        bC = make_box(tb4[baseC + t]);
        cC = clamp_cls(tlabels[baseC + t]);
    }

    int tile = blockIdx.x;
    if (tile >= numTiles) return;   // nwg <= numTiles by launch, never taken

    // ---- Prefetch tile 0 into registers.
    float xcur[RPB];
    float4 pbcur = {0.0f, 0.0f, 0.0f, 0.0f};
    {
        const int n0 = tile * RPB;
#pragma unroll
        for (int r = 0; r < RPB; ++r) {
            int n = n0 + r; n = n < N - 1 ? n : N - 1;
            xcur[r] = logits[(size_t)n * NC + t];
        }
        if (t < RPB) {
            int n = n0 + t; n = n < N - 1 ? n : N - 1;
            pbcur = pb4[n];
        }
    }

    bool bsel = false;
    for (; tile < numTiles; tile += nwg) {
        const int n0   = tile * RPB;
        const int rows = (N - n0 < RPB) ? (N - n0) : RPB;
        float (*fcb)[NC] = bsel ? fc[1] : fc[0];
        float (*ppb)[8]  = bsel ? pp[1] : pp[0];

        // ---- Focal + row params for this tile (from prefetched regs). ----
#pragma unroll
        for (int r = 0; r < RPB; ++r) {
            if (r < rows) {
                const float x = xcur[r];
                const float p = __builtin_amdgcn_rcpf(1.0f + __expf(-x));
                const float q = 1.0f - p;
                const float pos = ALPHAc * q * q * (-__logf(p + EPSc));
                const float neg = (1.0f - ALPHAc) * p * p * (-__logf(q + EPSc));
                fcb[r][t] = fmaf(2.0f, pos - neg, 2.0f);
            }
        }
        if (t < rows) {
            const float4 pb = pbcur;
            ppb[t][0] = fmaf(-0.5f, pb.z, pb.x);
            ppb[t][1] = fmaf(-0.5f, pb.w, pb.y);
            ppb[t][2] = fmaf( 0.5f, pb.z, pb.x);
            ppb[t][3] = fmaf( 0.5f, pb.w, pb.y);
            ppb[t][4] = pb.z * pb.w;
            ppb[t][5] = pb.z + pb.z;
            ppb[t][6] = pb.w + pb.w;
            ppb[t][7] = 0.0f;
        }
        __syncthreads();

        // ---- Prefetch NEXT tile now — before any store is issued, so the
        //      vmcnt wait at the next focal only covers these loads. ----
        const int ntile = tile + nwg;
        float xnext[RPB];
        float4 pbnext = pbcur;
        if (ntile < numTiles) {
            const int nn0 = ntile * RPB;
#pragma unroll
            for (int r = 0; r < RPB; ++r) {
                int n = nn0 + r; n = n < N - 1 ? n : N - 1;
                xnext[r] = logits[(size_t)n * NC + t];
            }
            if (t < RPB) {
                int n = nn0 + t; n = n < N - 1 ? n : N - 1;
                pbnext = pb4[n];
            }
        } else {
#pragma unroll
            for (int r = 0; r < RPB; ++r) xnext[r] = 0.0f;
        }

        const float* fr = &fcb[0][0];

        if (rows == RPB) {
            // ================= straight-line fast path =================
            // ---- Phase A: 4 targets/thread, float4 stores. ----
            if (aV) {
                const float* g0 = fr + cA0;
                const float* g1 = fr + cA1;
                const float* g2 = fr + cA2;
                const float* g3 = fr + cA3;
                float fA[RPB][4];             // statically indexed -> registers
#pragma unroll
                for (int r = 0; r < RPB; ++r) {
                    fA[r][0] = g0[r * NC];
                    fA[r][1] = g1[r * NC];
                    fA[r][2] = g2[r * NC];
                    fA[r][3] = g3[r * NC];
                }
#pragma unroll
                for (int r = 0; r < RPB; ++r) {
                    const float4 p0 = *reinterpret_cast<const float4*>(&ppb[r][0]);
                    const float4 p1 = *reinterpret_cast<const float4*>(&ppb[r][4]);
                    f32x4 res;
                    res.x = cost_elem(p0.x, p0.y, p0.z, p0.w, p1.x, p1.y, p1.z, bA0, fA[r][0]);
                    res.y = cost_elem(p0.x, p0.y, p0.z, p0.w, p1.x, p1.y, p1.z, bA1, fA[r][1]);
                    res.z = cost_elem(p0.x, p0.y, p0.z, p0.w, p1.x, p1.y, p1.z, bA2, fA[r][2]);
                    res.w = cost_elem(p0.x, p0.y, p0.z, p0.w, p1.x, p1.y, p1.z, bA3, fA[r][3]);
                    float* orow = out + (size_t)(n0 + r) * M;
                    __builtin_nontemporal_store(res, reinterpret_cast<f32x4*>(orow) + t);
                }
            }

            // ---- Phase B: 2 targets/thread, float2 stores. ----
            if (bV) {
                const float* g0 = fr + cB0;
                const float* g1 = fr + cB1;
                float fB[RPB][2];
#pragma unroll
                for (int r = 0; r < RPB; ++r) {
                    fB[r][0] = g0[r * NC];
                    fB[r][1] = g1[r * NC];
                }
#pragma unroll
                for (int r = 0; r < RPB; ++r) {
                    const float4 p0 = *reinterpret_cast<const float4*>(&ppb[r][0]);
                    const float4 p1 = *reinterpret_cast<const float4*>(&ppb[r][4]);
                    f32x2 res;
                    res.x = cost_elem(p0.x, p0.y, p0.z, p0.w, p1.x, p1.y, p1.z, bB0, fB[r][0]);
                    res.y = cost_elem(p0.x, p0.y, p0.z, p0.w, p1.x, p1.y, p1.z, bB1, fB[r][1]);
                    float* orow = out + (size_t)(n0 + r) * M + baseB;
                    __builtin_nontemporal_store(res, reinterpret_cast<f32x2*>(orow) + t);
                }
            }

            // ---- Phase C: scalar tail (64 lanes for M=1600). ----
            if (cV) {
                const int e = baseC + t;
                const float* g = fr + cC;
                float fCv[RPB];
#pragma unroll
                for (int r = 0; r < RPB; ++r) fCv[r] = g[r * NC];
#pragma unroll
                for (int r = 0; r < RPB; ++r) {
                    const float4 p0 = *reinterpret_cast<const float4*>(&ppb[r][0]);
                    const float4 p1 = *reinterpret_cast<const float4*>(&ppb[r][4]);
                    const float v = cost_elem(p0.x, p0.y, p0.z, p0.w, p1.x, p1.y, p1.z, bC, fCv[r]);
                    __builtin_nontemporal_store(v, out + (size_t)(n0 + r) * M + e);
                }
            }
            // Extra tail beyond one stride (not hit for M=1600; cold path).
            for (int e = baseC + NT + t; e < M; e += NT) {
                const TBox b = make_box(tb4[e]);
                const float* g = fr + clamp_cls(tlabels[e]);
#pragma unroll
                for (int r = 0; r < RPB; ++r) {
                    const float4 p0 = *reinterpret_cast<const float4*>(&ppb[r][0]);
                    const float4 p1 = *reinterpret_cast<const float4*>(&ppb[r][4]);
                    const float v = cost_elem(p0.x, p0.y, p0.z, p0.w, p1.x, p1.y, p1.z, b, g[r * NC]);
                    __builtin_nontemporal_store(v, out + (size_t)(n0 + r) * M + e);
                }
            }
        } else {
            // ============ generic fallback (never hit for N=16000) ============
            for (int r = 0; r < rows; ++r) {
                const float4 p0 = *reinterpret_cast<const float4*>(&ppb[r][0]);
                const float4 p1 = *reinterpret_cast<const float4*>(&ppb[r][4]);
                for (int e = t; e < M; e += NT) {
                    const TBox b = make_box(tb4[e]);
                    const float f = fr[clamp_cls(tlabels[e]) + r * NC];
                    out[(size_t)(n0 + r) * M + e] =
                        cost_elem(p0.x, p0.y, p0.z, p0.w, p1.x, p1.y, p1.z, b, f);
                }
            }
        }

        // ---- Rotate prefetch registers; flip LDS buffer. ----
#pragma unroll
        for (int r = 0; r < RPB; ++r) xcur[r] = xnext[r];
        pbcur = pbnext;
        bsel = !bsel;
    }
}

extern "C" void kernel_launch(void* const* d_in, const int* in_sizes, int n_in,
                              void* d_out, int out_size, void* d_ws, size_t ws_size,
                              hipStream_t stream) {
    const float* logits  = (const float*)d_in[0];   // [16,1000,256] f32
    const float* pboxes  = (const float*)d_in[1];   // [16,1000,4]  f32
    const int*   tlabels = (const int*)d_in[2];     // [1600] i32
    const float* tboxes  = (const float*)d_in[3];   // [1600,4] f32

    float* out = (float*)d_out;

    const int N = in_sizes[1] / 4;   // 16000 pred rows
    const int M = in_sizes[2];       // 1600 targets

    const int numTiles = (N + RPB - 1) / RPB;           // 2000
    const int nblocks  = numTiles < MAXWG ? numTiles : MAXWG;  // 500
    hipLaunchKernelGGL(hungarian_cost_kernel, dim3(nblocks), dim3(NT), 0, stream,
                       logits, pboxes, tlabels, tboxes, out, N, M);
}

// Round 11
// 38.290 us; speedup vs baseline: 1.2162x; 1.1217x over previous
//
#include <hip/hip_runtime.h>

// HungarianMatcher cost matrix: C[n,m] = 5*L1(boxes) + 2*focal_class - 2*GIoU
// logits [N=16000, NC=256] f32, pred_boxes [N,4] cxcywh f32,
// tgt_labels [M=1600] i32, tgt_boxes [M,4] cxcywh f32, out [N,M] f32.
//
// Round-7 champion structure (33.2us), single change: plain stores instead of
// nontemporal (NT bypasses L2 -> HBM-latency completion -> store-queue
// backpressure stalls the wave; plain stores complete in L2 and drain async).

constexpr float ALPHAc = 0.25f;
constexpr float EPSc   = 1e-8f;

constexpr int NC  = 256;  // classes (== blockDim.x)
constexpr int NT  = 256;  // threads per block
constexpr int RPB = 8;    // rows per block (16000 % 8 == 0 -> 2000 blocks, all full)

typedef float f32x4 __attribute__((ext_vector_type(4)));
typedef float f32x2 __attribute__((ext_vector_type(2)));

struct TBox { float x0, y0, x1, y1, area; };

__device__ __forceinline__ TBox make_box(float4 b) {
    TBox r;
    r.x0 = fmaf(-0.5f, b.z, b.x);
    r.y0 = fmaf(-0.5f, b.w, b.y);
    r.x1 = fmaf( 0.5f, b.z, b.x);
    r.y1 = fmaf( 0.5f, b.w, b.y);
    r.area = b.z * b.w;
    return r;
}

__device__ __forceinline__ const float* fc_base(const float* fc0, int c) {
    c = c < 0 ? 0 : (c > NC - 1 ? NC - 1 : c);
    return fc0 + c;
}

// res = 5*L1 + (2*fc+2) - 2*(inter/uni + uni/carea)
__device__ __forceinline__ float cost_elem(float px0, float py0, float px1, float py1,
                                           float parea, float pw2, float ph2,
                                           const TBox& b, float fcp) {
    const float u0 = b.x0 - px0, u1 = b.x1 - px1;
    const float v0 = b.y0 - py0, v1 = b.y1 - py1;
    const float du = u1 - u0,    dv = v1 - v0;
    const float l1 = fmaf(0.5f, fabsf(u0 + u1), fabsf(du))
                   + fmaf(0.5f, fabsf(v0 + v1), fabsf(dv));
    const float ix0 = fmaxf(px0, b.x0), ix1 = fminf(px1, b.x1);
    const float iy0 = fmaxf(py0, b.y0), iy1 = fminf(py1, b.y1);
    const float iwr = ix1 - ix0, ihr = iy1 - iy0;
    const float inter = fmaxf(iwr, 0.0f) * fmaxf(ihr, 0.0f);
    const float uni   = (parea + b.area) - inter;
    const float cw = (pw2 + du) - iwr;
    const float ch = (ph2 + dv) - ihr;
    const float carea = cw * ch;
    const float num = fmaf(uni, uni, inter * carea);
    const float mm  = num * __builtin_amdgcn_rcpf(uni * carea);
    return fmaf(-2.0f, mm, fmaf(5.0f, l1, fcp));
}

__global__ __launch_bounds__(NT)
void hungarian_cost_kernel(const float* __restrict__ logits,
                           const float* __restrict__ pboxes,
                           const int*   __restrict__ tlabels,
                           const float* __restrict__ tboxes,
                           float*       __restrict__ out,
                           int N, int M)
{
    const int t  = threadIdx.x;
    const int n0 = blockIdx.x * RPB;
    if (n0 >= N) return;
    const int rows = (N - n0 < RPB) ? (N - n0) : RPB;

    __shared__ float fc[RPB][NC];   // 2*focal+2, per row per class
    __shared__ float pp[RPB][8];    // px0,py0,px1,py1,parea,pw2,ph2,pad per row

    // ---- Prologue: focal costs + row params. ONE barrier. ----
#pragma unroll
    for (int r = 0; r < RPB; ++r) {
        if (r < rows) {
            const float x = logits[(size_t)(n0 + r) * NC + t];
            const float p = __builtin_amdgcn_rcpf(1.0f + __expf(-x));
            const float q = 1.0f - p;
            const float pos = ALPHAc * q * q * (-__logf(p + EPSc));
            const float neg = (1.0f - ALPHAc) * p * p * (-__logf(q + EPSc));
            fc[r][t] = fmaf(2.0f, pos - neg, 2.0f);
        }
    }
    if (t < rows) {
        const float4 pb = reinterpret_cast<const float4*>(pboxes)[n0 + t];
        pp[t][0] = fmaf(-0.5f, pb.z, pb.x);
        pp[t][1] = fmaf(-0.5f, pb.w, pb.y);
        pp[t][2] = fmaf( 0.5f, pb.z, pb.x);
        pp[t][3] = fmaf( 0.5f, pb.w, pb.y);
        pp[t][4] = pb.z * pb.w;
        pp[t][5] = pb.z + pb.z;
        pp[t][6] = pb.w + pb.w;
        pp[t][7] = 0.0f;
    }
    __syncthreads();

    const float4* tb4 = reinterpret_cast<const float4*>(tboxes);
    const float*  fc0 = &fc[0][0];

    // m-layout: nA float4 groups, nB float2 groups, scalar tail.
    // M=1600: 256*4 + 256*2 + 64*1.
    const int nA    = (M >> 2) < NT ? (M >> 2) : NT;
    const int baseB = 4 * nA;
    const int nB    = ((M - baseB) >> 1) < NT ? ((M - baseB) >> 1) : NT;
    const int baseC = baseB + 2 * nB;

    if (rows == RPB) {
        // ===================== straight-line fast path =====================

        // ---- Phase A: 4 targets/thread, float4 stores. ----
        if (t < nA) {
            const int4 c4 = reinterpret_cast<const int4*>(tlabels)[t];
            const TBox b0 = make_box(tb4[4 * t + 0]);
            const TBox b1 = make_box(tb4[4 * t + 1]);
            const TBox b2 = make_box(tb4[4 * t + 2]);
            const TBox b3 = make_box(tb4[4 * t + 3]);
            const float* g0 = fc_base(fc0, c4.x);
            const float* g1 = fc_base(fc0, c4.y);
            const float* g2 = fc_base(fc0, c4.z);
            const float* g3 = fc_base(fc0, c4.w);
            float fA[RPB][4];               // statically indexed -> registers
#pragma unroll
            for (int r = 0; r < RPB; ++r) { // 32 ds_read_b32, all issued up-front
                fA[r][0] = g0[r * NC];
                fA[r][1] = g1[r * NC];
                fA[r][2] = g2[r * NC];
                fA[r][3] = g3[r * NC];
            }
#pragma unroll
            for (int r = 0; r < RPB; ++r) {
                const float4 p0 = *reinterpret_cast<const float4*>(&pp[r][0]);
                const float4 p1 = *reinterpret_cast<const float4*>(&pp[r][4]);
                f32x4 res;
                res.x = cost_elem(p0.x, p0.y, p0.z, p0.w, p1.x, p1.y, p1.z, b0, fA[r][0]);
                res.y = cost_elem(p0.x, p0.y, p0.z, p0.w, p1.x, p1.y, p1.z, b1, fA[r][1]);
                res.z = cost_elem(p0.x, p0.y, p0.z, p0.w, p1.x, p1.y, p1.z, b2, fA[r][2]);
                res.w = cost_elem(p0.x, p0.y, p0.z, p0.w, p1.x, p1.y, p1.z, b3, fA[r][3]);
                float* orow = out + (size_t)(n0 + r) * M;
                reinterpret_cast<f32x4*>(orow)[t] = res;
            }
        }

        // ---- Phase B: 2 targets/thread, float2 stores. ----
        if (t < nB) {
            const int2 c2 = reinterpret_cast<const int2*>(tlabels + baseB)[t];
            const TBox b0 = make_box(tb4[baseB + 2 * t + 0]);
            const TBox b1 = make_box(tb4[baseB + 2 * t + 1]);
            const float* g0 = fc_base(fc0, c2.x);
            const float* g1 = fc_base(fc0, c2.y);
            float fB[RPB][2];
#pragma unroll
            for (int r = 0; r < RPB; ++r) {
                fB[r][0] = g0[r * NC];
                fB[r][1] = g1[r * NC];
            }
#pragma unroll
            for (int r = 0; r < RPB; ++r) {
                const float4 p0 = *reinterpret_cast<const float4*>(&pp[r][0]);
                const float4 p1 = *reinterpret_cast<const float4*>(&pp[r][4]);
                f32x2 res;
                res.x = cost_elem(p0.x, p0.y, p0.z, p0.w, p1.x, p1.y, p1.z, b0, fB[r][0]);
                res.y = cost_elem(p0.x, p0.y, p0.z, p0.w, p1.x, p1.y, p1.z, b1, fB[r][1]);
                float* orow = out + (size_t)(n0 + r) * M + baseB;
                reinterpret_cast<f32x2*>(orow)[t] = res;
            }
        }

        // ---- Phase C: scalar tail (64 lanes for M=1600). ----
        if (baseC + t < M) {
            const int e = baseC + t;
            const TBox b = make_box(tb4[e]);
            const float* g = fc_base(fc0, tlabels[e]);
            float fC[RPB];
#pragma unroll
            for (int r = 0; r < RPB; ++r) fC[r] = g[r * NC];
#pragma unroll
            for (int r = 0; r < RPB; ++r) {
                const float4 p0 = *reinterpret_cast<const float4*>(&pp[r][0]);
                const float4 p1 = *reinterpret_cast<const float4*>(&pp[r][4]);
                const float v = cost_elem(p0.x, p0.y, p0.z, p0.w, p1.x, p1.y, p1.z, b, fC[r]);
                out[(size_t)(n0 + r) * M + e] = v;
            }
        }
        // Extra tail beyond one stride (not hit for M=1600).
        for (int e = baseC + NT + t; e < M; e += NT) {
            const TBox b = make_box(tb4[e]);
            const float* g = fc_base(fc0, tlabels[e]);
#pragma unroll
            for (int r = 0; r < RPB; ++r) {
                const float4 p0 = *reinterpret_cast<const float4*>(&pp[r][0]);
                const float4 p1 = *reinterpret_cast<const float4*>(&pp[r][4]);
                const float v = cost_elem(p0.x, p0.y, p0.z, p0.w, p1.x, p1.y, p1.z, b, g[r * NC]);
                out[(size_t)(n0 + r) * M + e] = v;
            }
        }
    } else {
        // ===================== generic fallback (never hit for N=16000) =====
        for (int r = 0; r < rows; ++r) {
            const float4 p0 = *reinterpret_cast<const float4*>(&pp[r][0]);
            const float4 p1 = *reinterpret_cast<const float4*>(&pp[r][4]);
            for (int e = t; e < M; e += NT) {
                const TBox b = make_box(tb4[e]);
                const float f = *fc_base(fc0 + r * NC, tlabels[e]);
                out[(size_t)(n0 + r) * M + e] =
                    cost_elem(p0.x, p0.y, p0.z, p0.w, p1.x, p1.y, p1.z, b, f);
            }
        }
    }
}

extern "C" void kernel_launch(void* const* d_in, const int* in_sizes, int n_in,
                              void* d_out, int out_size, void* d_ws, size_t ws_size,
                              hipStream_t stream) {
    const float* logits  = (const float*)d_in[0];   // [16,1000,256] f32
    const float* pboxes  = (const float*)d_in[1];   // [16,1000,4]  f32
    const int*   tlabels = (const int*)d_in[2];     // [1600] i32
    const float* tboxes  = (const float*)d_in[3];   // [1600,4] f32

    float* out = (float*)d_out;

    const int N = in_sizes[1] / 4;   // 16000 pred rows
    const int M = in_sizes[2];       // 1600 targets

    const int nblocks = (N + RPB - 1) / RPB;   // 2000
    hipLaunchKernelGGL(hungarian_cost_kernel, dim3(nblocks), dim3(NT), 0, stream,
                       logits, pboxes, tlabels, tboxes, out, N, M);
}

// Round 12
// 32.822 us; speedup vs baseline: 1.4189x; 1.1666x over previous
//
#include <hip/hip_runtime.h>

// HungarianMatcher cost matrix: C[n,m] = 5*L1(boxes) + 2*focal_class - 2*GIoU
// logits [N=16000, NC=256] f32, pred_boxes [N,4] cxcywh f32,
// tgt_labels [M=1600] i32, tgt_boxes [M,4] cxcywh f32, out [N,M] f32.
//
// Round-7 champion structure (33.2us, NT stores). Single change: targets are
// processed in PAIRS as f32x2 SoA so the compiler can emit CDNA4 packed-fp32
// (v_pk_add/mul/fma_f32, 2 elems/inst) for the add/mul/fma majority of
// cost_elem. Arithmetic is bit-identical f32.

constexpr float ALPHAc = 0.25f;
constexpr float EPSc   = 1e-8f;

constexpr int NC  = 256;  // classes (== blockDim.x)
constexpr int NT  = 256;  // threads per block
constexpr int RPB = 8;    // rows per block (16000 % 8 == 0 -> 2000 blocks, all full)

typedef float f32x4 __attribute__((ext_vector_type(4)));
typedef float f32x2 __attribute__((ext_vector_type(2)));

struct TBox  { float x0, y0, x1, y1, area; };
struct TBox2 { f32x2 x0, y0, x1, y1, area; };   // 2 targets, SoA

__device__ __forceinline__ TBox make_box(float4 b) {
    TBox r;
    r.x0 = fmaf(-0.5f, b.z, b.x);
    r.y0 = fmaf(-0.5f, b.w, b.y);
    r.x1 = fmaf( 0.5f, b.z, b.x);
    r.y1 = fmaf( 0.5f, b.w, b.y);
    r.area = b.z * b.w;
    return r;
}

__device__ __forceinline__ TBox2 make_box2(float4 a, float4 b) {
    TBox2 r;
    r.x0 = f32x2{fmaf(-0.5f, a.z, a.x), fmaf(-0.5f, b.z, b.x)};
    r.y0 = f32x2{fmaf(-0.5f, a.w, a.y), fmaf(-0.5f, b.w, b.y)};
    r.x1 = f32x2{fmaf( 0.5f, a.z, a.x), fmaf( 0.5f, b.z, b.x)};
    r.y1 = f32x2{fmaf( 0.5f, a.w, a.y), fmaf( 0.5f, b.w, b.y)};
    r.area = f32x2{a.z * a.w, b.z * b.w};
    return r;
}

__device__ __forceinline__ const float* fc_base(const float* fc0, int c) {
    c = c < 0 ? 0 : (c > NC - 1 ? NC - 1 : c);
    return fc0 + c;
}

// Scalar reference path (phase C + fallback).
__device__ __forceinline__ float cost_elem(float px0, float py0, float px1, float py1,
                                           float parea, float pw2, float ph2,
                                           const TBox& b, float fcp) {
    const float u0 = b.x0 - px0, u1 = b.x1 - px1;
    const float v0 = b.y0 - py0, v1 = b.y1 - py1;
    const float du = u1 - u0,    dv = v1 - v0;
    const float l1 = fmaf(0.5f, fabsf(u0 + u1), fabsf(du))
                   + fmaf(0.5f, fabsf(v0 + v1), fabsf(dv));
    const float ix0 = fmaxf(px0, b.x0), ix1 = fminf(px1, b.x1);
    const float iy0 = fmaxf(py0, b.y0), iy1 = fminf(py1, b.y1);
    const float iwr = ix1 - ix0, ihr = iy1 - iy0;
    const float inter = fmaxf(iwr, 0.0f) * fmaxf(ihr, 0.0f);
    const float uni   = (parea + b.area) - inter;
    const float cw = (pw2 + du) - iwr;
    const float ch = (ph2 + dv) - ihr;
    const float carea = cw * ch;
    const float num = fmaf(uni, uni, inter * carea);
    const float mm  = num * __builtin_amdgcn_rcpf(uni * carea);
    return fmaf(-2.0f, mm, fmaf(5.0f, l1, fcp));
}

// Packed pair path: same ops on f32x2 -> v_pk_{add,mul,fma}_f32 where possible.
__device__ __forceinline__ f32x2 cost_elem2(float px0, float py0, float px1, float py1,
                                            float parea, float pw2, float ph2,
                                            const TBox2& b, f32x2 fcp) {
    const f32x2 vpx0 = px0, vpy0 = py0, vpx1 = px1, vpy1 = py1;
    const f32x2 u0 = b.x0 - vpx0, u1 = b.x1 - vpx1;
    const f32x2 v0 = b.y0 - vpy0, v1 = b.y1 - vpy1;
    const f32x2 du = u1 - u0,     dv = v1 - v0;
    const f32x2 half = 0.5f;
    const f32x2 l1 = __builtin_elementwise_fma(half, __builtin_elementwise_abs(u0 + u1),
                                               __builtin_elementwise_abs(du))
                   + __builtin_elementwise_fma(half, __builtin_elementwise_abs(v0 + v1),
                                               __builtin_elementwise_abs(dv));
    const f32x2 ix0 = __builtin_elementwise_max(vpx0, b.x0);
    const f32x2 ix1 = __builtin_elementwise_min(vpx1, b.x1);
    const f32x2 iy0 = __builtin_elementwise_max(vpy0, b.y0);
    const f32x2 iy1 = __builtin_elementwise_min(vpy1, b.y1);
    const f32x2 iwr = ix1 - ix0, ihr = iy1 - iy0;
    const f32x2 zero = 0.0f;
    const f32x2 inter = __builtin_elementwise_max(iwr, zero)
                      * __builtin_elementwise_max(ihr, zero);
    const f32x2 uni = (b.area + parea) - inter;
    const f32x2 cw = (du + pw2) - iwr;
    const f32x2 ch = (dv + ph2) - ihr;
    const f32x2 carea = cw * ch;
    const f32x2 num = __builtin_elementwise_fma(uni, uni, inter * carea);
    const f32x2 den = uni * carea;
    const f32x2 rcp = f32x2{__builtin_amdgcn_rcpf(den.x), __builtin_amdgcn_rcpf(den.y)};
    const f32x2 mm = num * rcp;
    const f32x2 five = 5.0f, m2 = -2.0f;
    return __builtin_elementwise_fma(m2, mm, __builtin_elementwise_fma(five, l1, fcp));
}

__global__ __launch_bounds__(NT)
void hungarian_cost_kernel(const float* __restrict__ logits,
                           const float* __restrict__ pboxes,
                           const int*   __restrict__ tlabels,
                           const float* __restrict__ tboxes,
                           float*       __restrict__ out,
                           int N, int M)
{
    const int t  = threadIdx.x;
    const int n0 = blockIdx.x * RPB;
    if (n0 >= N) return;
    const int rows = (N - n0 < RPB) ? (N - n0) : RPB;

    __shared__ float fc[RPB][NC];   // 2*focal+2, per row per class
    __shared__ float pp[RPB][8];    // px0,py0,px1,py1,parea,pw2,ph2,pad per row

    // ---- Prologue: focal costs + row params. ONE barrier. ----
#pragma unroll
    for (int r = 0; r < RPB; ++r) {
        if (r < rows) {
            const float x = logits[(size_t)(n0 + r) * NC + t];
            const float p = __builtin_amdgcn_rcpf(1.0f + __expf(-x));
            const float q = 1.0f - p;
            const float pos = ALPHAc * q * q * (-__logf(p + EPSc));
            const float neg = (1.0f - ALPHAc) * p * p * (-__logf(q + EPSc));
            fc[r][t] = fmaf(2.0f, pos - neg, 2.0f);
        }
    }
    if (t < rows) {
        const float4 pb = reinterpret_cast<const float4*>(pboxes)[n0 + t];
        pp[t][0] = fmaf(-0.5f, pb.z, pb.x);
        pp[t][1] = fmaf(-0.5f, pb.w, pb.y);
        pp[t][2] = fmaf( 0.5f, pb.z, pb.x);
        pp[t][3] = fmaf( 0.5f, pb.w, pb.y);
        pp[t][4] = pb.z * pb.w;
        pp[t][5] = pb.z + pb.z;
        pp[t][6] = pb.w + pb.w;
        pp[t][7] = 0.0f;
    }
    __syncthreads();

    const float4* tb4 = reinterpret_cast<const float4*>(tboxes);
    const float*  fc0 = &fc[0][0];

    // m-layout: nA float4 groups, nB float2 groups, scalar tail.
    // M=1600: 256*4 + 256*2 + 64*1.
    const int nA    = (M >> 2) < NT ? (M >> 2) : NT;
    const int baseB = 4 * nA;
    const int nB    = ((M - baseB) >> 1) < NT ? ((M - baseB) >> 1) : NT;
    const int baseC = baseB + 2 * nB;

    if (rows == RPB) {
        // ===================== straight-line fast path =====================

        // ---- Phase A: 4 targets/thread = 2 packed pairs, float4 NT stores. ----
        if (t < nA) {
            const int4 c4 = reinterpret_cast<const int4*>(tlabels)[t];
            const TBox2 p01 = make_box2(tb4[4 * t + 0], tb4[4 * t + 1]);
            const TBox2 p23 = make_box2(tb4[4 * t + 2], tb4[4 * t + 3]);
            const float* g0 = fc_base(fc0, c4.x);
            const float* g1 = fc_base(fc0, c4.y);
            const float* g2 = fc_base(fc0, c4.z);
            const float* g3 = fc_base(fc0, c4.w);
            float fA[RPB][4];               // statically indexed -> registers
#pragma unroll
            for (int r = 0; r < RPB; ++r) { // 32 ds_read_b32 issued up-front
                fA[r][0] = g0[r * NC];
                fA[r][1] = g1[r * NC];
                fA[r][2] = g2[r * NC];
                fA[r][3] = g3[r * NC];
            }
#pragma unroll
            for (int r = 0; r < RPB; ++r) {
                const float4 p0 = *reinterpret_cast<const float4*>(&pp[r][0]);
                const float4 p1 = *reinterpret_cast<const float4*>(&pp[r][4]);
                const f32x2 r01 = cost_elem2(p0.x, p0.y, p0.z, p0.w, p1.x, p1.y, p1.z,
                                             p01, f32x2{fA[r][0], fA[r][1]});
                const f32x2 r23 = cost_elem2(p0.x, p0.y, p0.z, p0.w, p1.x, p1.y, p1.z,
                                             p23, f32x2{fA[r][2], fA[r][3]});
                f32x4 res;
                res.x = r01.x; res.y = r01.y; res.z = r23.x; res.w = r23.y;
                float* orow = out + (size_t)(n0 + r) * M;
                __builtin_nontemporal_store(res, reinterpret_cast<f32x4*>(orow) + t);
            }
        }

        // ---- Phase B: 2 targets/thread = 1 packed pair, float2 NT stores. ----
        if (t < nB) {
            const int2 c2 = reinterpret_cast<const int2*>(tlabels + baseB)[t];
            const TBox2 pB = make_box2(tb4[baseB + 2 * t + 0], tb4[baseB + 2 * t + 1]);
            const float* g0 = fc_base(fc0, c2.x);
            const float* g1 = fc_base(fc0, c2.y);
            float fB[RPB][2];
#pragma unroll
            for (int r = 0; r < RPB; ++r) {
                fB[r][0] = g0[r * NC];
                fB[r][1] = g1[r * NC];
            }
#pragma unroll
            for (int r = 0; r < RPB; ++r) {
                const float4 p0 = *reinterpret_cast<const float4*>(&pp[r][0]);
                const float4 p1 = *reinterpret_cast<const float4*>(&pp[r][4]);
                const f32x2 res = cost_elem2(p0.x, p0.y, p0.z, p0.w, p1.x, p1.y, p1.z,
                                             pB, f32x2{fB[r][0], fB[r][1]});
                float* orow = out + (size_t)(n0 + r) * M + baseB;
                __builtin_nontemporal_store(res, reinterpret_cast<f32x2*>(orow) + t);
            }
        }

        // ---- Phase C: scalar tail (64 lanes for M=1600). ----
        if (baseC + t < M) {
            const int e = baseC + t;
            const TBox b = make_box(tb4[e]);
            const float* g = fc_base(fc0, tlabels[e]);
            float fC[RPB];
#pragma unroll
            for (int r = 0; r < RPB; ++r) fC[r] = g[r * NC];
#pragma unroll
            for (int r = 0; r < RPB; ++r) {
                const float4 p0 = *reinterpret_cast<const float4*>(&pp[r][0]);
                const float4 p1 = *reinterpret_cast<const float4*>(&pp[r][4]);
                const float v = cost_elem(p0.x, p0.y, p0.z, p0.w, p1.x, p1.y, p1.z, b, fC[r]);
                __builtin_nontemporal_store(v, out + (size_t)(n0 + r) * M + e);
            }
        }
        // Extra tail beyond one stride (not hit for M=1600).
        for (int e = baseC + NT + t; e < M; e += NT) {
            const TBox b = make_box(tb4[e]);
            const float* g = fc_base(fc0, tlabels[e]);
#pragma unroll
            for (int r = 0; r < RPB; ++r) {
                const float4 p0 = *reinterpret_cast<const float4*>(&pp[r][0]);
                const float4 p1 = *reinterpret_cast<const float4*>(&pp[r][4]);
                const float v = cost_elem(p0.x, p0.y, p0.z, p0.w, p1.x, p1.y, p1.z, b, g[r * NC]);
                __builtin_nontemporal_store(v, out + (size_t)(n0 + r) * M + e);
            }
        }
    } else {
        // ===================== generic fallback (never hit for N=16000) =====
        for (int r = 0; r < rows; ++r) {
            const float4 p0 = *reinterpret_cast<const float4*>(&pp[r][0]);
            const float4 p1 = *reinterpret_cast<const float4*>(&pp[r][4]);
            for (int e = t; e < M; e += NT) {
                const TBox b = make_box(tb4[e]);
                const float f = *fc_base(fc0 + r * NC, tlabels[e]);
                out[(size_t)(n0 + r) * M + e] =
                    cost_elem(p0.x, p0.y, p0.z, p0.w, p1.x, p1.y, p1.z, b, f);
            }
        }
    }
}

extern "C" void kernel_launch(void* const* d_in, const int* in_sizes, int n_in,
                              void* d_out, int out_size, void* d_ws, size_t ws_size,
                              hipStream_t stream) {
    const float* logits  = (const float*)d_in[0];   // [16,1000,256] f32
    const float* pboxes  = (const float*)d_in[1];   // [16,1000,4]  f32
    const int*   tlabels = (const int*)d_in[2];     // [1600] i32
    const float* tboxes  = (const float*)d_in[3];   // [1600,4] f32

    float* out = (float*)d_out;

    const int N = in_sizes[1] / 4;   // 16000 pred rows
    const int M = in_sizes[2];       // 1600 targets

    const int nblocks = (N + RPB - 1) / RPB;   // 2000
    hipLaunchKernelGGL(hungarian_cost_kernel, dim3(nblocks), dim3(NT), 0, stream,
                       logits, pboxes, tlabels, tboxes, out, N, M);
}